// Round 2
// baseline (509.298 us; speedup 1.0000x reference)
//
#include <hip/hip_runtime.h>
#include <stdint.h>
#include <math.h>

// SwitchFeedForwardTail: x (2,1024,768) f32, Ws (768,9), W1 (9,768,3072),
// W2 (9,3072,768). Output needs only expert-0 ("common") and routes[t]
// ("sel") per token -> <= 2 FFN evals/token instead of 9 (4.5x FLOP cut).
#define T_TOK 2048
#define DM 768
#define DF 3072
#define NE 9

typedef unsigned short ushort_t;
typedef __attribute__((ext_vector_type(8))) __bf16 bf16x8;
typedef __attribute__((ext_vector_type(4))) float f32x4;

__device__ __forceinline__ unsigned short f2bf(float f) {
  union { float f; uint32_t u; } v; v.f = f;
  uint32_t u = v.u;
  u = u + 0x7fffu + ((u >> 16) & 1u);   // round-to-nearest-even
  return (unsigned short)(u >> 16);
}

__device__ __forceinline__ void gl_lds16(const void* g, void* l) {
  __builtin_amdgcn_global_load_lds(
      (const __attribute__((address_space(1))) unsigned int*)g,
      (__attribute__((address_space(3))) unsigned int*)l, 16, 0, 0);
}

// ---------------- routing: logits = x @ Ws + bs, softmax, p/argmax ----------
// one wave per token; also emits x in bf16 (fused conversion).
__global__ __launch_bounds__(256) void route_kernel(
    const float* __restrict__ x, const float* __restrict__ Ws,
    const float* __restrict__ bs, ushort_t* __restrict__ xb,
    float* __restrict__ p, int* __restrict__ routes,
    int* __restrict__ counts, int* __restrict__ lists) {
  const int wave = threadIdx.x >> 6, lane = threadIdx.x & 63;
  const int t = blockIdx.x * 4 + wave;
  const float* xr = x + (size_t)t * DM;
  const int d0 = lane * 12;                      // 768 = 64 lanes * 12
  float xv[12];
#pragma unroll
  for (int i = 0; i < 12; ++i) xv[i] = xr[d0 + i];
#pragma unroll
  for (int i = 0; i < 3; ++i) {
    ushort4 s;
    s.x = f2bf(xv[i * 4 + 0]); s.y = f2bf(xv[i * 4 + 1]);
    s.z = f2bf(xv[i * 4 + 2]); s.w = f2bf(xv[i * 4 + 3]);
    *(ushort4*)(xb + (size_t)t * DM + d0 + i * 4) = s;
  }
  float acc[NE];
#pragma unroll
  for (int e = 0; e < NE; ++e) acc[e] = 0.f;
#pragma unroll
  for (int i = 0; i < 12; ++i) {
    const float* wr = Ws + (size_t)(d0 + i) * NE;
#pragma unroll
    for (int e = 0; e < NE; ++e) acc[e] += xv[i] * wr[e];
  }
#pragma unroll
  for (int off = 32; off >= 1; off >>= 1)
#pragma unroll
    for (int e = 0; e < NE; ++e) acc[e] += __shfl_xor(acc[e], off);
  if (lane == 0) {
    float m = -1e30f; int am = 0;
#pragma unroll
    for (int e = 0; e < NE; ++e) {
      float l = acc[e] + bs[e];
      acc[e] = l;
      if (l > m) { m = l; am = e; }              // strict > : first max = argmax
    }
    float s = 0.f;
#pragma unroll
    for (int e = 0; e < NE; ++e) s += expf(acc[e] - m);
    p[t] = 1.0f / s;                             // prob of the max logit
    routes[t] = am;
    if (am != 0) {
      int pos = atomicAdd(&counts[am], 1);
      lists[(am - 1) * T_TOK + pos] = t;
    }
  }
}

// ------------- transpose + f32->bf16: in (E,R,C) -> out (E,C,R) -------------
// 64x64 tile, float4 loads, ushort4 stores (128B/wave contiguous).
// [64][65] pad -> 2-way bank aliasing only (free).
__global__ __launch_bounds__(256) void transpose_conv(
    const float* __restrict__ in, ushort_t* __restrict__ out,
    int R, int C) {
  __shared__ float tile[64][65];
  const int e = blockIdx.z;
  const float* src = in + (size_t)e * R * C;
  ushort_t* dst = out + (size_t)e * R * C;
  const int c0 = blockIdx.x * 64, r0 = blockIdx.y * 64;
  const int k = threadIdx.x & 15, g = threadIdx.x >> 4;   // 16 x 16
#pragma unroll
  for (int i = 0; i < 4; ++i) {
    const float4 v =
        *(const float4*)(src + (size_t)(r0 + g + i * 16) * C + c0 + k * 4);
    tile[g + i * 16][k * 4 + 0] = v.x;
    tile[g + i * 16][k * 4 + 1] = v.y;
    tile[g + i * 16][k * 4 + 2] = v.z;
    tile[g + i * 16][k * 4 + 3] = v.w;
  }
  __syncthreads();
#pragma unroll
  for (int i = 0; i < 4; ++i) {
    const int c = g + i * 16;                    // out row = c0 + c
    ushort4 s;
    s.x = f2bf(tile[k * 4 + 0][c]);
    s.y = f2bf(tile[k * 4 + 1][c]);
    s.z = f2bf(tile[k * 4 + 2][c]);
    s.w = f2bf(tile[k * 4 + 3][c]);
    *(ushort4*)(dst + (size_t)(c0 + c) * R + r0 + k * 4) = s;
  }
}

// ------------- grouped gather-GEMM, BMx128 tile, BK=64, 4 waves -------------
// Grid: (x = M-tiles [fastest -> same-B blocks adjacent], y = N-tiles, z = e)
// with bijective XCD-chunk swizzle (requires nwg % 8 == 0).
// A: rows gathered by token list (expert 0 = identity). B: (NE,N,K) bf16
// K-contiguous. PASS1: D = gelu(A@B+bias) -> bf16. else: D = A@B+bias -> f32.
template <int K, int N, int BM, bool PASS1>
__global__ __launch_bounds__(256) void ffn_gemm(
    const ushort_t* __restrict__ Asrc0, const ushort_t* __restrict__ AsrcS,
    const ushort_t* __restrict__ Btb, const float* __restrict__ bias,
    const int* __restrict__ counts, const int* __restrict__ lists,
    ushort_t* __restrict__ D0b, ushort_t* __restrict__ DSb,
    float* __restrict__ D0f, float* __restrict__ DSf) {
  const unsigned hw =
      (blockIdx.z * gridDim.y + blockIdx.y) * gridDim.x + blockIdx.x;
  const unsigned nwg = gridDim.x * gridDim.y * gridDim.z;
  const unsigned w = (hw & 7u) * (nwg >> 3) + (hw >> 3);  // nwg%8==0
  const int bx = w % gridDim.x;
  const unsigned t1 = w / gridDim.x;
  const int by = t1 % gridDim.y;
  const int e = t1 / gridDim.y;

  const int cnt = (e == 0) ? T_TOK : counts[e];
  const int m0 = bx * BM;
  if (m0 >= cnt) return;
  const int n0 = by * 128;
  const int* list = lists + (e - 1) * T_TOK;     // deref only when e>0
  const ushort_t* Asrc = (e == 0) ? Asrc0 : AsrcS;

  __shared__ ushort_t As[BM * 64];
  __shared__ ushort_t Bs[128 * 64];

  const int tid = threadIdx.x;
  const int wave = tid >> 6, lane = tid & 63;
  const int g = lane >> 4, lr = lane & 15;
  constexpr int AI = BM / 32;                    // A chunk-issues per wave
  constexpr int MR = BM / 32;                    // m-frags per wave (2 M-waves)

  const ushort_t* Bbase = Btb + ((size_t)e * N + n0) * K;

  // Chunk index XOR-preswizzled at the global source (both-sides rule #21):
  // LDS dest stays linear (global_load_lds requirement), ds_reads swizzle.
  const ushort_t* aSrcPtr[AI];
  const ushort_t* bSrcPtr[4];
#pragma unroll
  for (int i = 0; i < AI; ++i) {
    int cidx = (wave * AI + i) * 64 + lane;      // 16B chunk id
    int row = cidx >> 3;
    int ch = (cidx & 7) ^ (row & 7);
    int mrow = m0 + row;
    int tok = (e == 0) ? mrow : list[mrow < cnt ? mrow : cnt - 1];
    aSrcPtr[i] = Asrc + (size_t)tok * K + ch * 8;
  }
#pragma unroll
  for (int i = 0; i < 4; ++i) {
    int cidx = (wave * 4 + i) * 64 + lane;
    int row = cidx >> 3;
    int ch = (cidx & 7) ^ (row & 7);
    bSrcPtr[i] = Bbase + (size_t)row * K + ch * 8;
  }

  f32x4 acc[MR][4];
#pragma unroll
  for (int mi = 0; mi < MR; ++mi)
#pragma unroll
    for (int ni = 0; ni < 4; ++ni) acc[mi][ni] = (f32x4){0.f, 0.f, 0.f, 0.f};

  const int wm = wave >> 1, wn = wave & 1;
  const int swz = (lr & 7) << 4;

  for (int k0 = 0; k0 < K; k0 += 64) {
#pragma unroll
    for (int i = 0; i < AI; ++i)
      gl_lds16(aSrcPtr[i] + k0, &As[(wave * AI + i) * 512]);
#pragma unroll
    for (int i = 0; i < 4; ++i)
      gl_lds16(bSrcPtr[i] + k0, &Bs[(wave * 4 + i) * 512]);
    __syncthreads();
#pragma unroll
    for (int kk = 0; kk < 2; ++kk) {
      bf16x8 af[MR], bfv[4];
#pragma unroll
      for (int mi = 0; mi < MR; ++mi) {
        int row = wm * (MR * 16) + mi * 16 + lr;
        int off = row * 128 + ((kk * 64 + g * 16) ^ swz);
        af[mi] = *(const bf16x8*)((const char*)As + off);
      }
#pragma unroll
      for (int ni = 0; ni < 4; ++ni) {
        int row = wn * 64 + ni * 16 + lr;
        int off = row * 128 + ((kk * 64 + g * 16) ^ swz);
        bfv[ni] = *(const bf16x8*)((const char*)Bs + off);
      }
#pragma unroll
      for (int mi = 0; mi < MR; ++mi)
#pragma unroll
        for (int ni = 0; ni < 4; ++ni)
          acc[mi][ni] = __builtin_amdgcn_mfma_f32_16x16x32_bf16(
              af[mi], bfv[ni], acc[mi][ni], 0, 0, 0);
    }
    __syncthreads();
  }

  // Epilogue. C/D layout: col = lane&15, row = (lane>>4)*4 + reg  [m89].
#pragma unroll
  for (int mi = 0; mi < MR; ++mi) {
#pragma unroll
    for (int r = 0; r < 4; ++r) {
      const int mrow = m0 + wm * (MR * 16) + mi * 16 + g * 4 + r;
      if (mrow >= cnt) continue;
      const int tok = (e == 0) ? mrow : list[mrow];
#pragma unroll
      for (int ni = 0; ni < 4; ++ni) {
        const int col = n0 + wn * 64 + ni * 16 + lr;
        float v = acc[mi][ni][r] + bias[e * N + col];
        if constexpr (PASS1) {
          float gv = 0.5f * v * (1.0f + erff(v * 0.70710678118654752f));
          ushort_t* Dst = (e == 0) ? D0b : DSb;
          Dst[(size_t)tok * N + col] = f2bf(gv);
        } else {
          float* Dst = (e == 0) ? D0f : DSf;
          Dst[(size_t)tok * N + col] = v;
        }
      }
    }
  }
}

// ------------- final mix -----------------------------------------------------
__global__ __launch_bounds__(256) void combine_kernel(
    const float* __restrict__ Ocm, const float* __restrict__ Osel,
    const float* __restrict__ p, const int* __restrict__ routes,
    float* __restrict__ out) {
  const int idx = blockIdx.x * blockDim.x + threadIdx.x;  // one float4
  const int t = idx / (DM / 4);
  f32x4 cm = ((const f32x4*)Ocm)[idx];
  const int r = routes[t];
  f32x4 res;
  if (r == 0) {
    res = cm;
  } else {
    const float pe = p[t];
    f32x4 sl = ((const f32x4*)Osel)[idx];
    res = pe * sl + (1.0f - pe) * cm;
  }
  ((f32x4*)out)[idx] = res;
}

extern "C" void kernel_launch(void* const* d_in, const int* in_sizes, int n_in,
                              void* d_out, int out_size, void* d_ws,
                              size_t ws_size, hipStream_t stream) {
  const float* x  = (const float*)d_in[0];
  const float* Ws = (const float*)d_in[1];
  const float* bs = (const float*)d_in[2];
  const float* W1 = (const float*)d_in[3];
  const float* b1 = (const float*)d_in[4];
  const float* W2 = (const float*)d_in[5];
  const float* b2 = (const float*)d_in[6];
  float* out = (float*)d_out;
  char* ws = (char*)d_ws;

  // ws layout (~83.5 MB). Wtb reused: W1^T for pass1, then W2^T for pass2.
  constexpr size_t XB_OFF  = 0;
  constexpr size_t WTB_OFF = XB_OFF + (size_t)T_TOK * DM * 2;
  constexpr size_t H0_OFF  = WTB_OFF + (size_t)NE * DF * DM * 2;
  constexpr size_t HS_OFF  = H0_OFF + (size_t)T_TOK * DF * 2;
  constexpr size_t OC_OFF  = HS_OFF + (size_t)T_TOK * DF * 2;
  constexpr size_t OS_OFF  = OC_OFF + (size_t)T_TOK * DM * 4;
  constexpr size_t P_OFF   = OS_OFF + (size_t)T_TOK * DM * 4;
  constexpr size_t RT_OFF  = P_OFF + (size_t)T_TOK * 4;
  constexpr size_t CNT_OFF = RT_OFF + (size_t)T_TOK * 4;
  constexpr size_t LST_OFF = CNT_OFF + 64;

  ushort_t* xb   = (ushort_t*)(ws + XB_OFF);
  ushort_t* Wtb  = (ushort_t*)(ws + WTB_OFF);
  ushort_t* H0   = (ushort_t*)(ws + H0_OFF);
  ushort_t* Hsel = (ushort_t*)(ws + HS_OFF);
  float* Ocm     = (float*)(ws + OC_OFF);
  float* Osel    = (float*)(ws + OS_OFF);
  float* p       = (float*)(ws + P_OFF);
  int* routes    = (int*)(ws + RT_OFF);
  int* counts    = (int*)(ws + CNT_OFF);
  int* lists     = (int*)(ws + LST_OFF);

  hipMemsetAsync(counts, 0, 64, stream);
  route_kernel<<<T_TOK / 4, 256, 0, stream>>>(x, Ws, bs, xb, p, routes, counts,
                                              lists);
  // W1 (E,768,3072) -> Wtb (E,3072,768) bf16
  transpose_conv<<<dim3(DF / 64, DM / 64, NE), 256, 0, stream>>>(W1, Wtb, DM,
                                                                 DF);
  // GEMM1: grid (M-tiles=16, N-tiles=24, 9) = 3456 blocks (%8==0)
  ffn_gemm<DM, DF, 128, true>
      <<<dim3(T_TOK / 128, DF / 128, NE), 256, 0, stream>>>(
          xb, xb, Wtb, b1, counts, lists, H0, Hsel, nullptr, nullptr);
  // W2 (E,3072,768) -> Wtb (E,768,3072) bf16
  transpose_conv<<<dim3(DM / 64, DF / 64, NE), 256, 0, stream>>>(W2, Wtb, DF,
                                                                 DM);
  // GEMM2: BM=64 -> grid (32, 6, 9) = 1728 blocks (%8==0), 2x live blocks
  ffn_gemm<DF, DM, 64, false>
      <<<dim3(T_TOK / 64, DM / 128, NE), 256, 0, stream>>>(
          H0, Hsel, Wtb, b2, counts, lists, nullptr, nullptr, Ocm, Osel);
  combine_kernel<<<(T_TOK * DM / 4) / 256, 256, 0, stream>>>(Ocm, Osel, p,
                                                             routes, out);
}

// Round 3
// 392.156 us; speedup vs baseline: 1.2987x; 1.2987x over previous
//
#include <hip/hip_runtime.h>
#include <stdint.h>
#include <math.h>

// SwitchFeedForwardTail: x (2,1024,768) f32, Ws (768,9), W1 (9,768,3072),
// W2 (9,3072,768). Output needs only expert-0 ("common") and routes[t]
// ("sel") per token -> <= 2 FFN evals/token instead of 9 (4.5x FLOP cut).
#define T_TOK 2048
#define DM 768
#define DF 3072
#define NE 9

typedef unsigned short ushort_t;
typedef __attribute__((ext_vector_type(8))) __bf16 bf16x8;
typedef __attribute__((ext_vector_type(4))) float f32x4;

__device__ __forceinline__ unsigned short f2bf(float f) {
  union { float f; uint32_t u; } v; v.f = f;
  uint32_t u = v.u;
  u = u + 0x7fffu + ((u >> 16) & 1u);   // round-to-nearest-even
  return (unsigned short)(u >> 16);
}

__device__ __forceinline__ void gl_lds16(const void* g, void* l) {
  __builtin_amdgcn_global_load_lds(
      (const __attribute__((address_space(1))) unsigned int*)g,
      (__attribute__((address_space(3))) unsigned int*)l, 16, 0, 0);
}

// ---------------- routing: logits = x @ Ws + bs, softmax, p/argmax ----------
// one wave per token; also emits x in bf16 (fused conversion).
__global__ __launch_bounds__(256) void route_kernel(
    const float* __restrict__ x, const float* __restrict__ Ws,
    const float* __restrict__ bs, ushort_t* __restrict__ xb,
    float* __restrict__ p, int* __restrict__ routes,
    int* __restrict__ counts, int* __restrict__ lists) {
  const int wave = threadIdx.x >> 6, lane = threadIdx.x & 63;
  const int t = blockIdx.x * 4 + wave;
  const float* xr = x + (size_t)t * DM;
  const int d0 = lane * 12;                      // 768 = 64 lanes * 12
  float xv[12];
#pragma unroll
  for (int i = 0; i < 12; ++i) xv[i] = xr[d0 + i];
#pragma unroll
  for (int i = 0; i < 3; ++i) {
    ushort4 s;
    s.x = f2bf(xv[i * 4 + 0]); s.y = f2bf(xv[i * 4 + 1]);
    s.z = f2bf(xv[i * 4 + 2]); s.w = f2bf(xv[i * 4 + 3]);
    *(ushort4*)(xb + (size_t)t * DM + d0 + i * 4) = s;
  }
  float acc[NE];
#pragma unroll
  for (int e = 0; e < NE; ++e) acc[e] = 0.f;
#pragma unroll
  for (int i = 0; i < 12; ++i) {
    const float* wr = Ws + (size_t)(d0 + i) * NE;
#pragma unroll
    for (int e = 0; e < NE; ++e) acc[e] += xv[i] * wr[e];
  }
#pragma unroll
  for (int off = 32; off >= 1; off >>= 1)
#pragma unroll
    for (int e = 0; e < NE; ++e) acc[e] += __shfl_xor(acc[e], off);
  if (lane == 0) {
    float m = -1e30f; int am = 0;
#pragma unroll
    for (int e = 0; e < NE; ++e) {
      float l = acc[e] + bs[e];
      acc[e] = l;
      if (l > m) { m = l; am = e; }              // strict > : first max = argmax
    }
    float s = 0.f;
#pragma unroll
    for (int e = 0; e < NE; ++e) s += expf(acc[e] - m);
    p[t] = 1.0f / s;                             // prob of the max logit
    routes[t] = am;
    if (am != 0) {
      int pos = atomicAdd(&counts[am], 1);
      lists[(am - 1) * T_TOK + pos] = t;
    }
  }
}

// ------------- transpose + f32->bf16: in (E,R,C) -> out (E,C,R) -------------
// 64x64 tile, float4 loads, ushort4 stores (128B/wave contiguous).
// [64][65] pad -> 2-way bank aliasing only (free).
__global__ __launch_bounds__(256) void transpose_conv(
    const float* __restrict__ in, ushort_t* __restrict__ out,
    int R, int C) {
  __shared__ float tile[64][65];
  const int e = blockIdx.z;
  const float* src = in + (size_t)e * R * C;
  ushort_t* dst = out + (size_t)e * R * C;
  const int c0 = blockIdx.x * 64, r0 = blockIdx.y * 64;
  const int k = threadIdx.x & 15, g = threadIdx.x >> 4;   // 16 x 16
#pragma unroll
  for (int i = 0; i < 4; ++i) {
    const float4 v =
        *(const float4*)(src + (size_t)(r0 + g + i * 16) * C + c0 + k * 4);
    tile[g + i * 16][k * 4 + 0] = v.x;
    tile[g + i * 16][k * 4 + 1] = v.y;
    tile[g + i * 16][k * 4 + 2] = v.z;
    tile[g + i * 16][k * 4 + 3] = v.w;
  }
  __syncthreads();
#pragma unroll
  for (int i = 0; i < 4; ++i) {
    const int c = g + i * 16;                    // out row = c0 + c
    ushort4 s;
    s.x = f2bf(tile[k * 4 + 0][c]);
    s.y = f2bf(tile[k * 4 + 1][c]);
    s.z = f2bf(tile[k * 4 + 2][c]);
    s.w = f2bf(tile[k * 4 + 3][c]);
    *(ushort4*)(dst + (size_t)(c0 + c) * R + r0 + k * 4) = s;
  }
}

// ------------- grouped gather-GEMM, BMx128 tile, BK=64, 4 waves -------------
// 1-D grid with PANEL-AFFINITY XCD mapping: raw id r -> XCD c = r&7 owns
// panels p=(by,e) with p%8==c; a panel's M-tiles are consecutive on that XCD
// (B panel stays in one XCD L2; dense expert-0 panels spread across XCDs).
// A: rows gathered by token list (expert 0 = identity). B: (NE,N,K) bf16
// K-contiguous. PASS1: D = gelu(A@B+bias) -> bf16. else: D = A@B+bias -> f32.
template <int K, int N, int BM, bool PASS1>
__global__ __launch_bounds__(256) void ffn_gemm(
    const ushort_t* __restrict__ Asrc0, const ushort_t* __restrict__ AsrcS,
    const ushort_t* __restrict__ Btb, const float* __restrict__ bias,
    const int* __restrict__ counts, const int* __restrict__ lists,
    ushort_t* __restrict__ D0b, ushort_t* __restrict__ DSb,
    float* __restrict__ D0f, float* __restrict__ DSf) {
  constexpr int GX = T_TOK / BM;                 // M-tiles
  constexpr int GY = N / 128;                    // N-tiles
  constexpr int P = GY * NE;                     // panels
  const unsigned r = blockIdx.x;
  const int c = r & 7u;                          // XCD (round-robin dispatch)
  const unsigned j = r >> 3;
  const int i = j / GX;                          // panel slot on this XCD
  const int k = j % GX;                          // M-tile within panel
  const int pid = c + 8 * i;
  if (pid >= P) return;
  const int by = pid % GY;
  const int e = pid / GY;

  const int cnt = (e == 0) ? T_TOK : counts[e];
  const int m0 = k * BM;
  if (m0 >= cnt) return;
  const int n0 = by * 128;
  const int* list = lists + (e - 1) * T_TOK;     // deref only when e>0
  const ushort_t* Asrc = (e == 0) ? Asrc0 : AsrcS;

  __shared__ ushort_t As[BM * 64];
  __shared__ ushort_t Bs[128 * 64];

  const int tid = threadIdx.x;
  const int wave = tid >> 6, lane = tid & 63;
  const int g = lane >> 4, lr = lane & 15;
  constexpr int AI = BM / 32;                    // A chunk-issues per wave
  constexpr int MR = BM / 32;                    // m-frags per wave (2 M-waves)

  const ushort_t* Bbase = Btb + ((size_t)e * N + n0) * K;

  // Chunk index XOR-preswizzled at the global source (both-sides rule #21):
  // LDS dest stays linear (global_load_lds requirement), ds_reads swizzle.
  const ushort_t* aSrcPtr[AI];
  const ushort_t* bSrcPtr[4];
#pragma unroll
  for (int ii = 0; ii < AI; ++ii) {
    int cidx = (wave * AI + ii) * 64 + lane;     // 16B chunk id
    int row = cidx >> 3;
    int ch = (cidx & 7) ^ (row & 7);
    int mrow = m0 + row;
    int tok = (e == 0) ? mrow : list[mrow < cnt ? mrow : cnt - 1];
    aSrcPtr[ii] = Asrc + (size_t)tok * K + ch * 8;
  }
#pragma unroll
  for (int ii = 0; ii < 4; ++ii) {
    int cidx = (wave * 4 + ii) * 64 + lane;
    int row = cidx >> 3;
    int ch = (cidx & 7) ^ (row & 7);
    bSrcPtr[ii] = Bbase + (size_t)row * K + ch * 8;
  }

  f32x4 acc[MR][4];
#pragma unroll
  for (int mi = 0; mi < MR; ++mi)
#pragma unroll
    for (int ni = 0; ni < 4; ++ni) acc[mi][ni] = (f32x4){0.f, 0.f, 0.f, 0.f};

  const int wm = wave >> 1, wn = wave & 1;
  const int swz = (lr & 7) << 4;

  for (int k0 = 0; k0 < K; k0 += 64) {
#pragma unroll
    for (int ii = 0; ii < AI; ++ii)
      gl_lds16(aSrcPtr[ii] + k0, &As[(wave * AI + ii) * 512]);
#pragma unroll
    for (int ii = 0; ii < 4; ++ii)
      gl_lds16(bSrcPtr[ii] + k0, &Bs[(wave * 4 + ii) * 512]);
    __syncthreads();
#pragma unroll
    for (int kk = 0; kk < 2; ++kk) {
      bf16x8 af[MR], bfv[4];
#pragma unroll
      for (int mi = 0; mi < MR; ++mi) {
        int row = wm * (MR * 16) + mi * 16 + lr;
        int off = row * 128 + ((kk * 64 + g * 16) ^ swz);
        af[mi] = *(const bf16x8*)((const char*)As + off);
      }
#pragma unroll
      for (int ni = 0; ni < 4; ++ni) {
        int row = wn * 64 + ni * 16 + lr;
        int off = row * 128 + ((kk * 64 + g * 16) ^ swz);
        bfv[ni] = *(const bf16x8*)((const char*)Bs + off);
      }
#pragma unroll
      for (int mi = 0; mi < MR; ++mi)
#pragma unroll
        for (int ni = 0; ni < 4; ++ni)
          acc[mi][ni] = __builtin_amdgcn_mfma_f32_16x16x32_bf16(
              af[mi], bfv[ni], acc[mi][ni], 0, 0, 0);
    }
    __syncthreads();
  }

  // Epilogue. C/D layout: col = lane&15, row = (lane>>4)*4 + reg  [m89].
#pragma unroll
  for (int mi = 0; mi < MR; ++mi) {
#pragma unroll
    for (int rr = 0; rr < 4; ++rr) {
      const int mrow = m0 + wm * (MR * 16) + mi * 16 + g * 4 + rr;
      if (mrow >= cnt) continue;
      const int tok = (e == 0) ? mrow : list[mrow];
#pragma unroll
      for (int ni = 0; ni < 4; ++ni) {
        const int col = n0 + wn * 64 + ni * 16 + lr;
        float v = acc[mi][ni][rr] + bias[e * N + col];
        if constexpr (PASS1) {
          float gv = 0.5f * v * (1.0f + erff(v * 0.70710678118654752f));
          ushort_t* Dst = (e == 0) ? D0b : DSb;
          Dst[(size_t)tok * N + col] = f2bf(gv);
        } else {
          float* Dst = (e == 0) ? D0f : DSf;
          Dst[(size_t)tok * N + col] = v;
        }
      }
    }
  }
}

// ------------- final mix -----------------------------------------------------
__global__ __launch_bounds__(256) void combine_kernel(
    const float* __restrict__ Ocm, const float* __restrict__ Osel,
    const float* __restrict__ p, const int* __restrict__ routes,
    float* __restrict__ out) {
  const int idx = blockIdx.x * blockDim.x + threadIdx.x;  // one float4
  const int t = idx / (DM / 4);
  f32x4 cm = ((const f32x4*)Ocm)[idx];
  const int r = routes[t];
  f32x4 res;
  if (r == 0) {
    res = cm;
  } else {
    const float pe = p[t];
    f32x4 sl = ((const f32x4*)Osel)[idx];
    res = pe * sl + (1.0f - pe) * cm;
  }
  ((f32x4*)out)[idx] = res;
}

extern "C" void kernel_launch(void* const* d_in, const int* in_sizes, int n_in,
                              void* d_out, int out_size, void* d_ws,
                              size_t ws_size, hipStream_t stream) {
  const float* x  = (const float*)d_in[0];
  const float* Ws = (const float*)d_in[1];
  const float* bs = (const float*)d_in[2];
  const float* W1 = (const float*)d_in[3];
  const float* b1 = (const float*)d_in[4];
  const float* W2 = (const float*)d_in[5];
  const float* b2 = (const float*)d_in[6];
  float* out = (float*)d_out;
  char* ws = (char*)d_ws;

  // ws layout (~83.5 MB). Wtb reused: W1^T for pass1, then W2^T for pass2.
  constexpr size_t XB_OFF  = 0;
  constexpr size_t WTB_OFF = XB_OFF + (size_t)T_TOK * DM * 2;
  constexpr size_t H0_OFF  = WTB_OFF + (size_t)NE * DF * DM * 2;
  constexpr size_t HS_OFF  = H0_OFF + (size_t)T_TOK * DF * 2;
  constexpr size_t OC_OFF  = HS_OFF + (size_t)T_TOK * DF * 2;
  constexpr size_t OS_OFF  = OC_OFF + (size_t)T_TOK * DM * 4;
  constexpr size_t P_OFF   = OS_OFF + (size_t)T_TOK * DM * 4;
  constexpr size_t RT_OFF  = P_OFF + (size_t)T_TOK * 4;
  constexpr size_t CNT_OFF = RT_OFF + (size_t)T_TOK * 4;
  constexpr size_t LST_OFF = CNT_OFF + 64;

  ushort_t* xb   = (ushort_t*)(ws + XB_OFF);
  ushort_t* Wtb  = (ushort_t*)(ws + WTB_OFF);
  ushort_t* H0   = (ushort_t*)(ws + H0_OFF);
  ushort_t* Hsel = (ushort_t*)(ws + HS_OFF);
  float* Ocm     = (float*)(ws + OC_OFF);
  float* Osel    = (float*)(ws + OS_OFF);
  float* p       = (float*)(ws + P_OFF);
  int* routes    = (int*)(ws + RT_OFF);
  int* counts    = (int*)(ws + CNT_OFF);
  int* lists     = (int*)(ws + LST_OFF);

  hipMemsetAsync(counts, 0, 64, stream);
  route_kernel<<<T_TOK / 4, 256, 0, stream>>>(x, Ws, bs, xb, p, routes, counts,
                                              lists);
  // W1 (E,768,3072) -> Wtb (E,3072,768) bf16
  transpose_conv<<<dim3(DF / 64, DM / 64, NE), 256, 0, stream>>>(W1, Wtb, DM,
                                                                 DF);
  // GEMM1: BM=128 -> GX=16, P=216 (27/XCD) -> grid 16*8*27 = 3456
  {
    constexpr int GX = T_TOK / 128, P = (DF / 128) * NE;
    constexpr int nblk = GX * 8 * ((P + 7) / 8);
    ffn_gemm<DM, DF, 128, true><<<nblk, 256, 0, stream>>>(
        xb, xb, Wtb, b1, counts, lists, H0, Hsel, nullptr, nullptr);
  }
  // W2 (E,3072,768) -> Wtb (E,768,3072) bf16
  transpose_conv<<<dim3(DM / 64, DF / 64, NE), 256, 0, stream>>>(W2, Wtb, DF,
                                                                 DM);
  // GEMM2: BM=64 -> GX=32, P=54 (7/XCD, 2 dead panels) -> grid 32*8*7 = 1792
  {
    constexpr int GX = T_TOK / 64, P = (DM / 128) * NE;
    constexpr int nblk = GX * 8 * ((P + 7) / 8);
    ffn_gemm<DF, DM, 64, false><<<nblk, 256, 0, stream>>>(
        H0, Hsel, Wtb, b2, counts, lists, nullptr, nullptr, Ocm, Osel);
  }
  combine_kernel<<<(T_TOK * DM / 4) / 256, 256, 0, stream>>>(Ocm, Osel, p,
                                                             routes, out);
}